// Round 11
// baseline (200.721 us; speedup 1.0000x reference)
//
#include <hip/hip_runtime.h>
#include <hip/hip_bf16.h>
#include <math.h>

typedef __hip_bfloat16 bf16;
typedef __attribute__((ext_vector_type(8))) short short8;
typedef __attribute__((ext_vector_type(4))) float f32x4;
typedef __attribute__((ext_vector_type(4))) unsigned int u32x4;

#define MFMA16(A, B, C) __builtin_amdgcn_mfma_f32_16x16x32_bf16((A), (B), (C), 0, 0, 0)
#define NEG_BIG (-1e30f)
#define EXP2(x) __builtin_amdgcn_exp2f(x)
// 0.125 (1/sqrt(d_k)) * log2(e): folded into Q at projection time -> scores in log2 domain
#define QSCALE 0.18033688011112042f

// two-register half-swaps (gfx950)
#define P32SWAP(a, b) asm("v_permlane32_swap_b32 %0, %1" : "+v"(a), "+v"(b))
#define P16SWAP(a, b) asm("v_permlane16_swap_b32 %0, %1" : "+v"(a), "+v"(b))

static __device__ __forceinline__ unsigned int cvt_pk_bf16(float lo, float hi) {
    unsigned int r;
    asm("v_cvt_pk_bf16_f32 %0, %1, %2" : "=v"(r) : "v"(lo), "v"(hi));
    return r;
}

// async global->LDS, 16B per lane; LDS dest is wave-uniform base + lane*16
static __device__ __forceinline__ void gload16(const bf16* g, void* l) {
    __builtin_amdgcn_global_load_lds(
        (const __attribute__((address_space(1))) void*)g,
        (__attribute__((address_space(3))) void*)l,
        16, 0, 0);
}

// fp32 -> bf16 round-to-nearest-even via bit ops
static __device__ __forceinline__ unsigned short f32_to_bf16_rne(float f) {
    unsigned int u = __float_as_uint(f);
    unsigned int rnd = 0x7FFFu + ((u >> 16) & 1u);
    return (unsigned short)((u + rnd) >> 16);
}

// In-kernel dtype detection (wave-uniform): scan first 64 shorts of x.
static __device__ __forceinline__ bool inputs_are_fp32(const unsigned short* x16) {
    int lane = threadIdx.x & 63;
    int e = (x16[lane] >> 7) & 0xFF;
    unsigned long long ball = __ballot(e >= 133);
    return __popcll(ball) >= 4;
}

// ---------------------------------------------------------------------------
// Kernel 0a: RoPE cos/sin table [s][p] float2, 2048 x 32 entries (512 KB).
// ---------------------------------------------------------------------------
__global__ __launch_bounds__(256) void rope_table(
    const int* __restrict__ pos, float2* __restrict__ tab)
{
    int i = blockIdx.x * 256 + threadIdx.x;   // 0..65535
    int s = i >> 5, p = i & 31;
    float freq = __expf((float)p * -0.28782313662425575f);
    float ang  = (float)pos[s] * freq;
    float sn, c;
    sincosf(ang, &sn, &c);
    tab[i] = make_float2(c, sn);
}

// ---------------------------------------------------------------------------
// Kernel 0b: canonical bf16 copies of all 5 inputs (fp32 path only).
// ---------------------------------------------------------------------------
__global__ __launch_bounds__(256) void convert_all(
    const void* __restrict__ xs, const void* __restrict__ wq,
    const void* __restrict__ wk, const void* __restrict__ wv,
    const void* __restrict__ wo,
    unsigned int* __restrict__ Xc, unsigned int* __restrict__ Wqc,
    unsigned int* __restrict__ Wkc, unsigned int* __restrict__ Wvc,
    unsigned int* __restrict__ Woc)
{
    if (!inputs_are_fp32((const unsigned short*)xs)) return;
    int i = blockIdx.x * 256 + threadIdx.x;  // 0 .. 4194303
    const float* src;
    unsigned int* dst;
    int off;
    if (i < 2097152) { src = (const float*)xs; dst = Xc; off = i; }
    else {
        int j = i - 2097152;
        int t = j >> 19;          // 0..3
        off = j & 524287;
        src = (const float*)((t == 0) ? wq : (t == 1) ? wk : (t == 2) ? wv : wo);
        dst = (t == 0) ? Wqc : (t == 1) ? Wkc : (t == 2) ? Wvc : Woc;
    }
    unsigned int lo = f32_to_bf16_rne(src[2 * off]);
    unsigned int hi = f32_to_bf16_rne(src[2 * off + 1]);
    dst[off] = (hi << 16) | lo;
}

// ---------------------------------------------------------------------------
// Kernel 1: QKV projection GEMM, 128x128 tile, BK=32 (round-4 m97-class:
// dbuf linear LDS + global_load_lds w16 + source-side swizzle, 1 barrier/K).
// grid = (32 m-tiles, 24 = 3 weights x 8 n-tiles), block = 256 (2x2 waves).
// Q,K: RoPE-table epilogue [b,h,s,d]. V: LDS-transposed [b,h,d,s].
// Q pre-scaled by 0.125*log2(e) -> flash softmax in exp2 domain.
// ---------------------------------------------------------------------------
__global__ __launch_bounds__(256, 1) void gemm_qkv_rope(
    const void* __restrict__ xr,
    const void* __restrict__ wqr, const void* __restrict__ wkr,
    const void* __restrict__ wvr,
    const bf16* __restrict__ Xc,
    const bf16* __restrict__ Wqc, const bf16* __restrict__ Wkc,
    const bf16* __restrict__ Wvc,
    const float2* __restrict__ rtab,
    bf16* __restrict__ Qb, bf16* __restrict__ Kb, bf16* __restrict__ Vt)
{
    const bool f32in = inputs_are_fp32((const unsigned short*)xr);
    const bf16* X = f32in ? Xc : (const bf16*)xr;

    // union: dbuf staging (2 x (A[128][32]+B[128][32]) = 16384 shorts)
    //        vs V-transpose tile (128x132 = 16896 shorts)
    __shared__ __align__(16) short smem[128 * 132];   // 33792 B

    const int m0   = blockIdx.x * 128;
    const int wsel = blockIdx.y >> 3;            // 0=Q, 1=K, 2=V
    const int n0   = (blockIdx.y & 7) * 128;
    const bf16* W  = (wsel == 0) ? (f32in ? Wqc : (const bf16*)wqr)
                   : (wsel == 1) ? (f32in ? Wkc : (const bf16*)wkr)
                                 : (f32in ? Wvc : (const bf16*)wvr);

    const int tid  = threadIdx.x;
    const int lane = tid & 63;
    const int wave = tid >> 6;
    const int wr   = wave >> 1, wc = wave & 1;   // 2x2 waves, each 64x64
    const int m    = lane & 15;
    const int q    = lane >> 4;

    const int stgrow = wave * 32 + (lane >> 2);
    const int ksegsh = (((lane & 3) ^ ((lane >> 3) & 3)) * 8);   // shorts
    const bf16* Ag = X + (m0 + stgrow) * 1024 + ksegsh;
    const bf16* Bg = W + (n0 + stgrow) * 1024 + ksegsh;
    char* const smemB = (char*)smem;
    const int aoff = ((q ^ ((m >> 1) & 3)) * 8);   // shorts within 32-short row

    f32x4 acc[4][4];
    #pragma unroll
    for (int mi = 0; mi < 4; ++mi)
        #pragma unroll
        for (int ni = 0; ni < 4; ++ni)
            acc[mi][ni] = (f32x4){0.f, 0.f, 0.f, 0.f};

    {
        char* la = smemB + wave * 2048;           // A buf0 + wave rows
        char* lb = smemB + 8192 + wave * 2048;    // B buf0
        gload16(Ag,            la);
        gload16(Ag + 16 * 1024, la + 1024);       // +16 rows
        gload16(Bg,            lb);
        gload16(Bg + 16 * 1024, lb + 1024);
    }

    for (int k0 = 0; k0 < 1024; k0 += 32) {
        const int bs = (k0 >> 5) & 1;
        __syncthreads();                           // buf[bs] landed (vmcnt drain)
        if (k0 + 32 < 1024) {                      // stage next into buf[bs^1]
            char* la = smemB + (bs ^ 1) * 16384 + wave * 2048;
            char* lb = la + 8192;
            gload16(Ag + (k0 + 32),             la);
            gload16(Ag + (k0 + 32) + 16 * 1024, la + 1024);
            gload16(Bg + (k0 + 32),             lb);
            gload16(Bg + (k0 + 32) + 16 * 1024, lb + 1024);
        }

        const short* As = smem + bs * 8192;        // shorts
        const short* Bs = As + 4096;
        short8 af[4], bfr[4];
        #pragma unroll
        for (int mi = 0; mi < 4; ++mi)
            af[mi] = *(const short8*)&As[(wr * 64 + mi * 16 + m) * 32 + aoff];
        #pragma unroll
        for (int ni = 0; ni < 4; ++ni)
            bfr[ni] = *(const short8*)&Bs[(wc * 64 + ni * 16 + m) * 32 + aoff];
        #pragma unroll
        for (int mi = 0; mi < 4; ++mi)
            #pragma unroll
            for (int ni = 0; ni < 4; ++ni)
                acc[mi][ni] = MFMA16(af[mi], bfr[ni], acc[mi][ni]);
    }

    const int bb  = m0 >> 11;
    const int s0  = m0 & 2047;
    const int hh0 = n0 >> 6;          // first of 2 heads in this n-tile

    if (wsel < 2) {
        bf16* dstb = (wsel == 0) ? Qb : Kb;
        const float sc = (wsel == 0) ? QSCALE : 1.0f;
        #pragma unroll
        for (int mi = 0; mi < 4; ++mi)
            #pragma unroll
            for (int ni = 0; ni < 4; ++ni)
                #pragma unroll
                for (int r = 0; r < 4; ++r) {
                    int s  = s0 + wr * 64 + mi * 16 + q * 4 + r;
                    int gn = n0 + wc * 64 + ni * 16 + m;
                    int hh = gn >> 6, d = gn & 63;
                    float v = acc[mi][ni][r];
                    float partner = __shfl_xor(v, 1);
                    float2 cs = rtab[s * 32 + (d >> 1)];
                    float outv = ((d & 1) == 0) ? (cs.x * v - cs.y * partner)
                                                : (cs.y * partner + cs.x * v);
                    dstb[((bb * 16 + hh) * 2048 + s) * 64 + d] =
                        __float2bfloat16(outv * sc);
                }
    } else {
        __syncthreads();   // all staging reads done before alias overwrite
        #pragma unroll
        for (int mi = 0; mi < 4; ++mi)
            #pragma unroll
            for (int ni = 0; ni < 4; ++ni)
                #pragma unroll
                for (int r = 0; r < 4; ++r) {
                    int ls = wr * 64 + mi * 16 + q * 4 + r;   // local s 0..127
                    int ld = wc * 64 + ni * 16 + m;           // local d 0..127
                    bf16 hv = __float2bfloat16(acc[mi][ni][r]);
                    smem[ld * 132 + ls] = *(short*)&hv;
                }
        __syncthreads();
        int dd = tid >> 1;            // 0..127: head hh0 + (dd>>6), d = dd&63
        int half = tid & 1;
        bf16* vrow = Vt + ((bb * 16 + hh0 + (dd >> 6)) * 64 + (dd & 63)) * 2048
                        + s0 + half * 64;
        #pragma unroll
        for (int j = 0; j < 8; ++j)
            *(short8*)(vrow + j * 8) =
                *(const short8*)&smem[dd * 132 + half * 64 + j * 8];
    }
}

// ---------------------------------------------------------------------------
// Kernel 2: causal flash attention, paired-qtile (512 balanced blocks,
// round-4 proven 2-barrier structure), KVBLK=256 (round-10).
// Two K-tiles per iteration: barriers/block 34->18, softmax state chain
// (rowmax-merge, alpha, mi/li, O-rescale, butterflies) runs half as often.
// nk4 = (qtile+4)>>2; pair sums = 9 for every pair (balance preserved).
// LDS: Ks[256][72] 36864 B + Vs[64][264] 33792 B = 70656 B -> 2 blocks/CU
// anti-phase overlap preserved. __launch_bounds__(256,2): 256-VGPR cap
// (round-8 lesson: never let the allocator target a tighter budget).
// ---------------------------------------------------------------------------
#define KST 72
#define VST2 264

__global__ __launch_bounds__(256, 2) void flash_attn(
    const bf16* __restrict__ Qb, const bf16* __restrict__ Kb,
    const bf16* __restrict__ Vt, bf16* __restrict__ ctx)
{
    const int pair = blockIdx.x;      // 0..15
    const int h = blockIdx.y, b = blockIdx.z;
    const int bh = b * 16 + h;

    __shared__ __align__(16) short Ks[256 * KST];   // 36864 B
    __shared__ __align__(16) short Vs[64 * VST2];   // 33792 B

    const int tid  = threadIdx.x;
    const int lane = tid & 63;
    const int wave = tid >> 6;
    const int m = lane & 15;
    const int q = lane >> 4;

    const int krow = tid >> 1;                 // 0..127 (also stages +128)
    const int kseg = (tid & 1) * 32;
    const int ksw  = ((krow >> 3) & 3) << 3;   // staging swizzle (shorts);
                                               // (krow+128) has same ksw
    const int vrow = tid >> 2;                 // 0..63 (d)
    const int vseg = (tid & 3) * 32;           // also stages +128

    const bf16* Kg = Kb + bh * 2048 * 64 + krow * 64   + kseg;
    const bf16* Vg = Vt + bh * 64 * 2048 + vrow * 2048 + vseg;

    for (int part = 0; part < 2; ++part) {
        const int qtile = (part == 0) ? pair : 31 - pair;
        const int nk4 = (qtile + 4) >> 2;
        const int rowbase = qtile * 64 + wave * 16;

        const bf16* Qp = Qb + (bh * 2048 + rowbase + m) * 64;
        short8 qf0 = *(const short8*)(Qp + q * 8);
        short8 qf1 = *(const short8*)(Qp + 32 + q * 8);

        f32x4 oacc[4];
        #pragma unroll
        for (int nb = 0; nb < 4; ++nb) oacc[nb] = (f32x4){0.f, 0.f, 0.f, 0.f};
        float mi_s = NEG_BIG, li_s = 0.f;   // per-lane softmax row = rowbase + m

        short8 kr[8], vr[8];
        #pragma unroll
        for (int j = 0; j < 4; ++j) {
            kr[j]     = *(const short8*)(Kg + j * 8);
            kr[j + 4] = *(const short8*)(Kg + 8192 + j * 8);   // rows +128
            vr[j]     = *(const short8*)(Vg + j * 8);
            vr[j + 4] = *(const short8*)(Vg + 128 + j * 8);    // cols +128
        }

        for (int kt4 = 0; kt4 < nk4; ++kt4) {
            __syncthreads();
            #pragma unroll
            for (int j = 0; j < 4; ++j) {
                *(short8*)&Ks[krow * KST + ((kseg + j * 8) ^ ksw)]         = kr[j];
                *(short8*)&Ks[(krow + 128) * KST + ((kseg + j * 8) ^ ksw)] = kr[j + 4];
                *(short8*)&Vs[vrow * VST2 + vseg + j * 8]       = vr[j];
                *(short8*)&Vs[vrow * VST2 + 128 + vseg + j * 8] = vr[j + 4];
            }
            __syncthreads();

            if (kt4 + 1 < nk4) {
                #pragma unroll
                for (int j = 0; j < 4; ++j) {
                    kr[j]     = *(const short8*)(Kg + (kt4 + 1) * 16384 + j * 8);
                    kr[j + 4] = *(const short8*)(Kg + (kt4 + 1) * 16384 + 8192 + j * 8);
                    vr[j]     = *(const short8*)(Vg + (kt4 + 1) * 256 + j * 8);
                    vr[j + 4] = *(const short8*)(Vg + (kt4 + 1) * 256 + 128 + j * 8);
                }
            }

            // swapped QK^T: S[q-row = m][key = kt4*256 + nc*16 + q*4 + r]
            f32x4 sacc[16];
            #pragma unroll
            for (int nc = 0; nc < 16; ++nc) {
                int row = nc * 16 + m;
                int sw  = ((row >> 3) & 3) << 3;
                const short* kp = &Ks[row * KST];
                short8 kf0 = *(const short8*)&kp[(q * 8) ^ sw];
                short8 kf1 = *(const short8*)&kp[32 + ((q * 8) ^ sw)];
                f32x4 z = {0.f, 0.f, 0.f, 0.f};
                z = MFMA16(kf0, qf0, z);
                z = MFMA16(kf1, qf1, z);
                sacc[nc] = z;
            }

            // causal mask (log2-domain scores; scale folded into Q)
            if (kt4 * 256 + 255 > rowbase) {
                int rowg = rowbase + m;
                #pragma unroll
                for (int nc = 0; nc < 16; ++nc)
                    #pragma unroll
                    for (int r = 0; r < 4; ++r) {
                        int col = kt4 * 256 + nc * 16 + q * 4 + r;
                        if (col > rowg) sacc[nc][r] = NEG_BIG;
                    }
            }

            // in-lane tree max + cross-q butterfly (lanes m,q=0..3 share row m)
            float tm[16];
            #pragma unroll
            for (int nc = 0; nc < 16; ++nc)
                tm[nc] = fmaxf(fmaxf(sacc[nc][0], sacc[nc][1]),
                               fmaxf(sacc[nc][2], sacc[nc][3]));
            float ta = fmaxf(fmaxf(fmaxf(tm[0], tm[1]), fmaxf(tm[2], tm[3])),
                             fmaxf(fmaxf(tm[4], tm[5]), fmaxf(tm[6], tm[7])));
            float tb = fmaxf(fmaxf(fmaxf(tm[8], tm[9]), fmaxf(tm[10], tm[11])),
                             fmaxf(fmaxf(tm[12], tm[13]), fmaxf(tm[14], tm[15])));
            float rm = fmaxf(ta, tb);
            rm = fmaxf(rm, __shfl_xor(rm, 16));
            rm = fmaxf(rm, __shfl_xor(rm, 32));
            float mnew  = fmaxf(mi_s, rm);
            float alpha = EXP2(mi_s - mnew);   // exp2(-inf)=0 on first tile
            mi_s = mnew;

            #pragma unroll
            for (int nc = 0; nc < 16; ++nc)
                #pragma unroll
                for (int r = 0; r < 4; ++r)
                    sacc[nc][r] = EXP2(sacc[nc][r] - mnew);  // masked -> 0

            float ts[16];
            #pragma unroll
            for (int nc = 0; nc < 16; ++nc)
                ts[nc] = (sacc[nc][0] + sacc[nc][1]) + (sacc[nc][2] + sacc[nc][3]);
            float sa = ((ts[0] + ts[1]) + (ts[2] + ts[3]))
                     + ((ts[4] + ts[5]) + (ts[6] + ts[7]));
            float sb = ((ts[8] + ts[9]) + (ts[10] + ts[11]))
                     + ((ts[12] + ts[13]) + (ts[14] + ts[15]));
            float asum = sa + sb;
            asum += __shfl_xor(asum, 16);
            asum += __shfl_xor(asum, 32);
            li_s = li_s * alpha + asum;

            // rescale O: output rows q*4+r live in lanes with m = q*4+r
            float ar[4];
            #pragma unroll
            for (int r = 0; r < 4; ++r) ar[r] = __shfl(alpha, q * 20 + r);
            #pragma unroll
            for (int nb = 0; nb < 4; ++nb)
                #pragma unroll
                for (int r = 0; r < 4; ++r) oacc[nb][r] *= ar[r];

            // pack P pairs to bf16 and route into PV A-fragments in-register.
            unsigned int u0[16], u1[16];
            #pragma unroll
            for (int nc = 0; nc < 16; ++nc) {
                u0[nc] = cvt_pk_bf16(sacc[nc][0], sacc[nc][1]);
                u1[nc] = cvt_pk_bf16(sacc[nc][2], sacc[nc][3]);
            }
            short8 pa[8];
            #pragma unroll
            for (int ck = 0; ck < 8; ++ck) {
                unsigned int x0 = u0[2 * ck], y0 = u0[2 * ck + 1];
                P32SWAP(x0, y0);
                P16SWAP(x0, y0);
                unsigned int x1 = u1[2 * ck], y1 = u1[2 * ck + 1];
                P32SWAP(x1, y1);
                P16SWAP(x1, y1);
                union { u32x4 u; short8 s; } uu;
                uu.u = (u32x4){x0, x1, y0, y1};
                pa[ck] = uu.s;
            }

            #pragma unroll
            for (int nb = 0; nb < 4; ++nb)
                #pragma unroll
                for (int ck = 0; ck < 8; ++ck) {
                    short8 vf = *(const short8*)&Vs[(nb * 16 + m) * VST2 + ck * 32 + q * 8];
                    oacc[nb] = MFMA16(pa[ck], vf, oacc[nb]);
                }
        }

        // epilogue: li for output row q*4+r lives in lanes m = q*4+r
        float lr[4];
        #pragma unroll
        for (int r = 0; r < 4; ++r) lr[r] = __shfl(li_s, q * 20 + r);
        #pragma unroll
        for (int r = 0; r < 4; ++r) {
            float inv = 1.f / lr[r];
            int srowg = qtile * 64 + wave * 16 + q * 4 + r;
            #pragma unroll
            for (int nb = 0; nb < 4; ++nb)
                ctx[(b * 2048 + srowg) * 1024 + h * 64 + nb * 16 + m] =
                    __float2bfloat16(oacc[nb][r] * inv);
        }
        __syncthreads();
    }
}

// ---------------------------------------------------------------------------
// Kernel 3: output projection, 128x128 tile — m97-class staging (round 4).
// grid = (32, 8), block = 256.
// ---------------------------------------------------------------------------
__global__ __launch_bounds__(256, 1) void gemm_out(
    const bf16* __restrict__ A,
    const void* __restrict__ wor, const bf16* __restrict__ Woc,
    const void* __restrict__ xr,
    void* __restrict__ out)
{
    const bool f32in = inputs_are_fp32((const unsigned short*)xr);
    const bf16* W = f32in ? Woc : (const bf16*)wor;

    __shared__ __align__(16) short smem[16384];   // 2 x (A+B) dbuf, 32768 B

    const int m0 = blockIdx.x * 128;
    const int n0 = blockIdx.y * 128;
    const int tid  = threadIdx.x;
    const int lane = tid & 63;
    const int wave = tid >> 6;
    const int wr = wave >> 1, wc = wave & 1;
    const int m = lane & 15, q = lane >> 4;

    const int stgrow = wave * 32 + (lane >> 2);
    const int ksegsh = (((lane & 3) ^ ((lane >> 3) & 3)) * 8);
    const bf16* Ag = A + (m0 + stgrow) * 1024 + ksegsh;
    const bf16* Bg = W + (n0 + stgrow) * 1024 + ksegsh;
    char* const smemB = (char*)smem;
    const int aoff = ((q ^ ((m >> 1) & 3)) * 8);

    f32x4 acc[4][4];
    #pragma unroll
    for (int mi = 0; mi < 4; ++mi)
        #pragma unroll
        for (int ni = 0; ni < 4; ++ni)
            acc[mi][ni] = (f32x4){0.f, 0.f, 0.f, 0.f};

    {
        char* la = smemB + wave * 2048;
        char* lb = smemB + 8192 + wave * 2048;
        gload16(Ag,            la);
        gload16(Ag + 16 * 1024, la + 1024);
        gload16(Bg,            lb);
        gload16(Bg + 16 * 1024, lb + 1024);
    }

    for (int k0 = 0; k0 < 1024; k0 += 32) {
        const int bs = (k0 >> 5) & 1;
        __syncthreads();
        if (k0 + 32 < 1024) {
            char* la = smemB + (bs ^ 1) * 16384 + wave * 2048;
            char* lb = la + 8192;
            gload16(Ag + (k0 + 32),             la);
            gload16(Ag + (k0 + 32) + 16 * 1024, la + 1024);
            gload16(Bg + (k0 + 32),             lb);
            gload16(Bg + (k0 + 32) + 16 * 1024, lb + 1024);
        }

        const short* As = smem + bs * 8192;
        const short* Bs = As + 4096;
        short8 af[4], bfr[4];
        #pragma unroll
        for (int mi = 0; mi < 4; ++mi)
            af[mi] = *(const short8*)&As[(wr * 64 + mi * 16 + m) * 32 + aoff];
        #pragma unroll
        for (int ni = 0; ni < 4; ++ni)
            bfr[ni] = *(const short8*)&Bs[(wc * 64 + ni * 16 + m) * 32 + aoff];
        #pragma unroll
        for (int mi = 0; mi < 4; ++mi)
            #pragma unroll
            for (int ni = 0; ni < 4; ++ni)
                acc[mi][ni] = MFMA16(af[mi], bfr[ni], acc[mi][ni]);
    }

    #pragma unroll
    for (int mi = 0; mi < 4; ++mi)
        #pragma unroll
        for (int ni = 0; ni < 4; ++ni)
            #pragma unroll
            for (int r = 0; r < 4; ++r) {
                int gm = m0 + wr * 64 + mi * 16 + q * 4 + r;
                int gn = n0 + wc * 64 + ni * 16 + m;
                int idx = gm * 1024 + gn;
                if (f32in) ((float*)out)[idx] = acc[mi][ni][r];
                else       ((bf16*)out)[idx]  = __float2bfloat16(acc[mi][ni][r]);
            }
}

// ---------------------------------------------------------------------------
extern "C" void kernel_launch(void* const* d_in, const int* in_sizes, int n_in,
                              void* d_out, int out_size, void* d_ws, size_t ws_size,
                              hipStream_t stream)
{
    const void* x_raw  = d_in[0];
    const void* Wq_raw = d_in[1];
    const void* Wk_raw = d_in[2];
    const void* Wv_raw = d_in[3];
    const void* Wo_raw = d_in[4];
    const int*  pos    = (const int*)d_in[5];

    char* ws = (char*)d_ws;
    bf16* Xc  = (bf16*)ws;                                    // 8 MB
    bf16* Wqc = (bf16*)(ws + 8388608);                        // 2 MB each
    bf16* Wkc = (bf16*)(ws + 8388608 + 2097152);
    bf16* Wvc = (bf16*)(ws + 8388608 + 2 * 2097152);
    bf16* Woc = (bf16*)(ws + 8388608 + 3 * 2097152);
    bf16* Qb  = (bf16*)(ws + 8388608 + 4 * 2097152);          // 8 MB each
    bf16* Kb  = Qb + 4194304;
    bf16* Vt  = Kb + 4194304;
    bf16* ctx = Vt + 4194304;
    float2* rtab = (float2*)(ctx + 4194304);                  // 512 KB

    rope_table<<<256, 256, 0, stream>>>(pos, rtab);
    convert_all<<<16384, 256, 0, stream>>>(
        x_raw, Wq_raw, Wk_raw, Wv_raw, Wo_raw,
        (unsigned int*)Xc, (unsigned int*)Wqc, (unsigned int*)Wkc,
        (unsigned int*)Wvc, (unsigned int*)Woc);

    gemm_qkv_rope<<<dim3(32, 24), 256, 0, stream>>>(
        x_raw, Wq_raw, Wk_raw, Wv_raw, Xc, Wqc, Wkc, Wvc, rtab, Qb, Kb, Vt);
    flash_attn<<<dim3(16, 16, 2), 256, 0, stream>>>(Qb, Kb, Vt, ctx);
    gemm_out<<<dim3(32, 8), 256, 0, stream>>>(ctx, Wo_raw, Woc, x_raw, d_out);
}

// Round 12
// 191.843 us; speedup vs baseline: 1.0463x; 1.0463x over previous
//
#include <hip/hip_runtime.h>
#include <hip/hip_bf16.h>
#include <math.h>

typedef __hip_bfloat16 bf16;
typedef __attribute__((ext_vector_type(8))) short short8;
typedef __attribute__((ext_vector_type(4))) float f32x4;
typedef __attribute__((ext_vector_type(4))) unsigned int u32x4;

#define MFMA16(A, B, C) __builtin_amdgcn_mfma_f32_16x16x32_bf16((A), (B), (C), 0, 0, 0)
#define NEG_BIG (-1e30f)
#define EXP2(x) __builtin_amdgcn_exp2f(x)
// 0.125 (1/sqrt(d_k)) * log2(e): folded into Q at projection time -> scores in log2 domain
#define QSCALE 0.18033688011112042f

// two-register half-swaps (gfx950)
#define P32SWAP(a, b) asm("v_permlane32_swap_b32 %0, %1" : "+v"(a), "+v"(b))
#define P16SWAP(a, b) asm("v_permlane16_swap_b32 %0, %1" : "+v"(a), "+v"(b))

static __device__ __forceinline__ unsigned int cvt_pk_bf16(float lo, float hi) {
    unsigned int r;
    asm("v_cvt_pk_bf16_f32 %0, %1, %2" : "=v"(r) : "v"(lo), "v"(hi));
    return r;
}

// async global->LDS, 16B per lane; LDS dest is wave-uniform base + lane*16
static __device__ __forceinline__ void gload16(const bf16* g, void* l) {
    __builtin_amdgcn_global_load_lds(
        (const __attribute__((address_space(1))) void*)g,
        (__attribute__((address_space(3))) void*)l,
        16, 0, 0);
}

// fp32 -> bf16 round-to-nearest-even via bit ops
static __device__ __forceinline__ unsigned short f32_to_bf16_rne(float f) {
    unsigned int u = __float_as_uint(f);
    unsigned int rnd = 0x7FFFu + ((u >> 16) & 1u);
    return (unsigned short)((u + rnd) >> 16);
}

// In-kernel dtype detection (wave-uniform): scan first 64 shorts of x.
static __device__ __forceinline__ bool inputs_are_fp32(const unsigned short* x16) {
    int lane = threadIdx.x & 63;
    int e = (x16[lane] >> 7) & 0xFF;
    unsigned long long ball = __ballot(e >= 133);
    return __popcll(ball) >= 4;
}

// ---------------------------------------------------------------------------
// Kernel 0: fused RoPE-table + bf16 canonicalization (round-11: one launch).
// Blocks >= 16384: rope cos/sin table [s][p] float2 (dtype-independent).
// Blocks < 16384: bf16 copies of all 5 inputs (fp32 path only).
// ---------------------------------------------------------------------------
__global__ __launch_bounds__(256) void convert_all(
    const void* __restrict__ xs, const void* __restrict__ wq,
    const void* __restrict__ wk, const void* __restrict__ wv,
    const void* __restrict__ wo,
    unsigned int* __restrict__ Xc, unsigned int* __restrict__ Wqc,
    unsigned int* __restrict__ Wkc, unsigned int* __restrict__ Wvc,
    unsigned int* __restrict__ Woc,
    const int* __restrict__ pos, float2* __restrict__ rtab)
{
    if (blockIdx.x >= 16384) {
        int i = (blockIdx.x - 16384) * 256 + threadIdx.x;   // 0..65535
        int s = i >> 5, p = i & 31;
        float freq = __expf((float)p * -0.28782313662425575f);
        float ang  = (float)pos[s] * freq;
        float sn, c;
        sincosf(ang, &sn, &c);
        rtab[i] = make_float2(c, sn);
        return;
    }
    if (!inputs_are_fp32((const unsigned short*)xs)) return;
    int i = blockIdx.x * 256 + threadIdx.x;  // 0 .. 4194303
    const float* src;
    unsigned int* dst;
    int off;
    if (i < 2097152) { src = (const float*)xs; dst = Xc; off = i; }
    else {
        int j = i - 2097152;
        int t = j >> 19;          // 0..3
        off = j & 524287;
        src = (const float*)((t == 0) ? wq : (t == 1) ? wk : (t == 2) ? wv : wo);
        dst = (t == 0) ? Wqc : (t == 1) ? Wkc : (t == 2) ? Wvc : Woc;
    }
    unsigned int lo = f32_to_bf16_rne(src[2 * off]);
    unsigned int hi = f32_to_bf16_rne(src[2 * off + 1]);
    dst[off] = (hi << 16) | lo;
}

// ---------------------------------------------------------------------------
// Kernel 1: QKV projection GEMM, 128x128 tile, BK=32 (round-4 m97-class:
// dbuf linear LDS + global_load_lds w16 + source-side swizzle, 1 barrier/K).
// grid = (32 m-tiles, 24 = 3 weights x 8 n-tiles), block = 256 (2x2 waves).
// Q,K: RoPE-table epilogue [b,h,s,d]. V: LDS-transposed [b,h,d,s].
// Q pre-scaled by 0.125*log2(e) -> flash softmax in exp2 domain.
// ---------------------------------------------------------------------------
__global__ __launch_bounds__(256, 1) void gemm_qkv_rope(
    const void* __restrict__ xr,
    const void* __restrict__ wqr, const void* __restrict__ wkr,
    const void* __restrict__ wvr,
    const bf16* __restrict__ Xc,
    const bf16* __restrict__ Wqc, const bf16* __restrict__ Wkc,
    const bf16* __restrict__ Wvc,
    const float2* __restrict__ rtab,
    bf16* __restrict__ Qb, bf16* __restrict__ Kb, bf16* __restrict__ Vt)
{
    const bool f32in = inputs_are_fp32((const unsigned short*)xr);
    const bf16* X = f32in ? Xc : (const bf16*)xr;

    // union: dbuf staging (2 x (A[128][32]+B[128][32]) = 16384 shorts)
    //        vs V-transpose tile (128x132 = 16896 shorts)
    __shared__ __align__(16) short smem[128 * 132];   // 33792 B

    const int m0   = blockIdx.x * 128;
    const int wsel = blockIdx.y >> 3;            // 0=Q, 1=K, 2=V
    const int n0   = (blockIdx.y & 7) * 128;
    const bf16* W  = (wsel == 0) ? (f32in ? Wqc : (const bf16*)wqr)
                   : (wsel == 1) ? (f32in ? Wkc : (const bf16*)wkr)
                                 : (f32in ? Wvc : (const bf16*)wvr);

    const int tid  = threadIdx.x;
    const int lane = tid & 63;
    const int wave = tid >> 6;
    const int wr   = wave >> 1, wc = wave & 1;   // 2x2 waves, each 64x64
    const int m    = lane & 15;
    const int q    = lane >> 4;

    const int stgrow = wave * 32 + (lane >> 2);
    const int ksegsh = (((lane & 3) ^ ((lane >> 3) & 3)) * 8);   // shorts
    const bf16* Ag = X + (m0 + stgrow) * 1024 + ksegsh;
    const bf16* Bg = W + (n0 + stgrow) * 1024 + ksegsh;
    char* const smemB = (char*)smem;
    const int aoff = ((q ^ ((m >> 1) & 3)) * 8);   // shorts within 32-short row

    f32x4 acc[4][4];
    #pragma unroll
    for (int mi = 0; mi < 4; ++mi)
        #pragma unroll
        for (int ni = 0; ni < 4; ++ni)
            acc[mi][ni] = (f32x4){0.f, 0.f, 0.f, 0.f};

    {
        char* la = smemB + wave * 2048;           // A buf0 + wave rows
        char* lb = smemB + 8192 + wave * 2048;    // B buf0
        gload16(Ag,            la);
        gload16(Ag + 16 * 1024, la + 1024);       // +16 rows
        gload16(Bg,            lb);
        gload16(Bg + 16 * 1024, lb + 1024);
    }

    for (int k0 = 0; k0 < 1024; k0 += 32) {
        const int bs = (k0 >> 5) & 1;
        __syncthreads();                           // buf[bs] landed (vmcnt drain)
        if (k0 + 32 < 1024) {                      // stage next into buf[bs^1]
            char* la = smemB + (bs ^ 1) * 16384 + wave * 2048;
            char* lb = la + 8192;
            gload16(Ag + (k0 + 32),             la);
            gload16(Ag + (k0 + 32) + 16 * 1024, la + 1024);
            gload16(Bg + (k0 + 32),             lb);
            gload16(Bg + (k0 + 32) + 16 * 1024, lb + 1024);
        }

        const short* As = smem + bs * 8192;        // shorts
        const short* Bs = As + 4096;
        short8 af[4], bfr[4];
        #pragma unroll
        for (int mi = 0; mi < 4; ++mi)
            af[mi] = *(const short8*)&As[(wr * 64 + mi * 16 + m) * 32 + aoff];
        #pragma unroll
        for (int ni = 0; ni < 4; ++ni)
            bfr[ni] = *(const short8*)&Bs[(wc * 64 + ni * 16 + m) * 32 + aoff];
        #pragma unroll
        for (int mi = 0; mi < 4; ++mi)
            #pragma unroll
            for (int ni = 0; ni < 4; ++ni)
                acc[mi][ni] = MFMA16(af[mi], bfr[ni], acc[mi][ni]);
    }

    const int bb  = m0 >> 11;
    const int s0  = m0 & 2047;
    const int hh0 = n0 >> 6;          // first of 2 heads in this n-tile

    if (wsel < 2) {
        bf16* dstb = (wsel == 0) ? Qb : Kb;
        const float sc = (wsel == 0) ? QSCALE : 1.0f;
        #pragma unroll
        for (int mi = 0; mi < 4; ++mi)
            #pragma unroll
            for (int ni = 0; ni < 4; ++ni)
                #pragma unroll
                for (int r = 0; r < 4; ++r) {
                    int s  = s0 + wr * 64 + mi * 16 + q * 4 + r;
                    int gn = n0 + wc * 64 + ni * 16 + m;
                    int hh = gn >> 6, d = gn & 63;
                    float v = acc[mi][ni][r];
                    float partner = __shfl_xor(v, 1);
                    float2 cs = rtab[s * 32 + (d >> 1)];
                    float outv = ((d & 1) == 0) ? (cs.x * v - cs.y * partner)
                                                : (cs.y * partner + cs.x * v);
                    dstb[((bb * 16 + hh) * 2048 + s) * 64 + d] =
                        __float2bfloat16(outv * sc);
                }
    } else {
        __syncthreads();   // all staging reads done before alias overwrite
        #pragma unroll
        for (int mi = 0; mi < 4; ++mi)
            #pragma unroll
            for (int ni = 0; ni < 4; ++ni)
                #pragma unroll
                for (int r = 0; r < 4; ++r) {
                    int ls = wr * 64 + mi * 16 + q * 4 + r;   // local s 0..127
                    int ld = wc * 64 + ni * 16 + m;           // local d 0..127
                    bf16 hv = __float2bfloat16(acc[mi][ni][r]);
                    smem[ld * 132 + ls] = *(short*)&hv;
                }
        __syncthreads();
        int dd = tid >> 1;            // 0..127: head hh0 + (dd>>6), d = dd&63
        int half = tid & 1;
        bf16* vrow = Vt + ((bb * 16 + hh0 + (dd >> 6)) * 64 + (dd & 63)) * 2048
                        + s0 + half * 64;
        #pragma unroll
        for (int j = 0; j < 8; ++j)
            *(short8*)(vrow + j * 8) =
                *(const short8*)&smem[dd * 132 + half * 64 + j * 8];
    }
}

// ---------------------------------------------------------------------------
// Kernel 2: causal flash attention — round-4 proven body, byte-identical
// (paired qtiles, 512 balanced blocks, 17 serial K-iterations, 2 barriers
// per iteration, single K/V buffer, no setprio; 51.3/52.0 us over 2 benches).
// Six structural variants (rounds 0,3,5,6,7-9,10) all regressed; this is
// the established floor of the family.
// ---------------------------------------------------------------------------
#define KST 72
#define VST 136

__global__ __launch_bounds__(256) void flash_attn(
    const bf16* __restrict__ Qb, const bf16* __restrict__ Kb,
    const bf16* __restrict__ Vt, bf16* __restrict__ ctx)
{
    const int pair = blockIdx.x;      // 0..15
    const int h = blockIdx.y, b = blockIdx.z;
    const int bh = b * 16 + h;

    __shared__ __align__(16) short Ks[128 * KST];
    __shared__ __align__(16) short Vs[64 * VST];

    const int tid  = threadIdx.x;
    const int lane = tid & 63;
    const int wave = tid >> 6;
    const int m = lane & 15;
    const int q = lane >> 4;

    const int krow = tid >> 1;
    const int kseg = (tid & 1) * 32;
    const int ksw  = ((krow >> 3) & 3) << 3;   // staging swizzle (shorts)
    const int vrow = tid >> 2;
    const int vseg = (tid & 3) * 32;

    const bf16* Kg = Kb + bh * 2048 * 64 + krow * 64   + kseg;
    const bf16* Vg = Vt + bh * 64 * 2048 + vrow * 2048 + vseg;

    for (int part = 0; part < 2; ++part) {
        const int qtile = (part == 0) ? pair : 31 - pair;
        const int nk2 = (qtile + 2) >> 1;
        const int rowbase = qtile * 64 + wave * 16;

        const bf16* Qp = Qb + (bh * 2048 + rowbase + m) * 64;
        short8 qf0 = *(const short8*)(Qp + q * 8);
        short8 qf1 = *(const short8*)(Qp + 32 + q * 8);

        f32x4 oacc[4];
        #pragma unroll
        for (int nb = 0; nb < 4; ++nb) oacc[nb] = (f32x4){0.f, 0.f, 0.f, 0.f};
        float mi_s = NEG_BIG, li_s = 0.f;   // per-lane softmax row = rowbase + m

        short8 kr[4], vr[4];
        #pragma unroll
        for (int j = 0; j < 4; ++j) {
            kr[j] = *(const short8*)(Kg + j * 8);
            vr[j] = *(const short8*)(Vg + j * 8);
        }

        for (int kt2 = 0; kt2 < nk2; ++kt2) {
            __syncthreads();
            #pragma unroll
            for (int j = 0; j < 4; ++j) {
                *(short8*)&Ks[krow * KST + ((kseg + j * 8) ^ ksw)] = kr[j];
                *(short8*)&Vs[vrow * VST + vseg + j * 8] = vr[j];
            }
            __syncthreads();

            if (kt2 + 1 < nk2) {
                #pragma unroll
                for (int j = 0; j < 4; ++j) {
                    kr[j] = *(const short8*)(Kg + (kt2 + 1) * 8192 + j * 8);
                    vr[j] = *(const short8*)(Vg + (kt2 + 1) * 128  + j * 8);
                }
            }

            // swapped QK^T: S[q-row = m][key = kt2*128 + nc*16 + q*4 + r]
            f32x4 sacc[8];
            #pragma unroll
            for (int nc = 0; nc < 8; ++nc) {
                int row = nc * 16 + m;
                int sw  = ((row >> 3) & 3) << 3;
                const short* kp = &Ks[row * KST];
                short8 kf0 = *(const short8*)&kp[(q * 8) ^ sw];
                short8 kf1 = *(const short8*)&kp[32 + ((q * 8) ^ sw)];
                f32x4 z = {0.f, 0.f, 0.f, 0.f};
                z = MFMA16(kf0, qf0, z);
                z = MFMA16(kf1, qf1, z);
                sacc[nc] = z;
            }

            // causal mask (log2-domain scores; scale folded into Q)
            if (kt2 * 128 + 127 > rowbase) {
                int rowg = rowbase + m;
                #pragma unroll
                for (int nc = 0; nc < 8; ++nc)
                    #pragma unroll
                    for (int r = 0; r < 4; ++r) {
                        int col = kt2 * 128 + nc * 16 + q * 4 + r;
                        if (col > rowg) sacc[nc][r] = NEG_BIG;
                    }
            }

            // in-lane tree max + cross-q butterfly (lanes m,q=0..3 share row m)
            float tm[8];
            #pragma unroll
            for (int nc = 0; nc < 8; ++nc)
                tm[nc] = fmaxf(fmaxf(sacc[nc][0], sacc[nc][1]),
                               fmaxf(sacc[nc][2], sacc[nc][3]));
            float rm = fmaxf(fmaxf(fmaxf(tm[0], tm[1]), fmaxf(tm[2], tm[3])),
                             fmaxf(fmaxf(tm[4], tm[5]), fmaxf(tm[6], tm[7])));
            rm = fmaxf(rm, __shfl_xor(rm, 16));
            rm = fmaxf(rm, __shfl_xor(rm, 32));
            float mnew  = fmaxf(mi_s, rm);
            float alpha = EXP2(mi_s - mnew);   // exp2(-inf)=0 on first tile
            mi_s = mnew;

            #pragma unroll
            for (int nc = 0; nc < 8; ++nc)
                #pragma unroll
                for (int r = 0; r < 4; ++r)
                    sacc[nc][r] = EXP2(sacc[nc][r] - mnew);  // masked -> 0

            float ts[8];
            #pragma unroll
            for (int nc = 0; nc < 8; ++nc)
                ts[nc] = (sacc[nc][0] + sacc[nc][1]) + (sacc[nc][2] + sacc[nc][3]);
            float asum = ((ts[0] + ts[1]) + (ts[2] + ts[3]))
                       + ((ts[4] + ts[5]) + (ts[6] + ts[7]));
            asum += __shfl_xor(asum, 16);
            asum += __shfl_xor(asum, 32);
            li_s = li_s * alpha + asum;

            // rescale O: output rows q*4+r live in lanes with m = q*4+r
            float ar[4];
            #pragma unroll
            for (int r = 0; r < 4; ++r) ar[r] = __shfl(alpha, q * 20 + r);
            #pragma unroll
            for (int nb = 0; nb < 4; ++nb)
                #pragma unroll
                for (int r = 0; r < 4; ++r) oacc[nb][r] *= ar[r];

            // pack P pairs to bf16 and route into PV A-fragments in-register.
            unsigned int u0[8], u1[8];
            #pragma unroll
            for (int nc = 0; nc < 8; ++nc) {
                u0[nc] = cvt_pk_bf16(sacc[nc][0], sacc[nc][1]);
                u1[nc] = cvt_pk_bf16(sacc[nc][2], sacc[nc][3]);
            }
            short8 pa[4];
            #pragma unroll
            for (int ck = 0; ck < 4; ++ck) {
                unsigned int x0 = u0[2 * ck], y0 = u0[2 * ck + 1];
                P32SWAP(x0, y0);
                P16SWAP(x0, y0);
                unsigned int x1 = u1[2 * ck], y1 = u1[2 * ck + 1];
                P32SWAP(x1, y1);
                P16SWAP(x1, y1);
                union { u32x4 u; short8 s; } uu;
                uu.u = (u32x4){x0, x1, y0, y1};
                pa[ck] = uu.s;
            }

            #pragma unroll
            for (int nb = 0; nb < 4; ++nb)
                #pragma unroll
                for (int ck = 0; ck < 4; ++ck) {
                    short8 vf = *(const short8*)&Vs[(nb * 16 + m) * VST + ck * 32 + q * 8];
                    oacc[nb] = MFMA16(pa[ck], vf, oacc[nb]);
                }
        }

        // epilogue: li for output row q*4+r lives in lanes m = q*4+r
        float lr[4];
        #pragma unroll
        for (int r = 0; r < 4; ++r) lr[r] = __shfl(li_s, q * 20 + r);
        #pragma unroll
        for (int r = 0; r < 4; ++r) {
            float inv = 1.f / lr[r];
            int srowg = qtile * 64 + wave * 16 + q * 4 + r;
            #pragma unroll
            for (int nb = 0; nb < 4; ++nb)
                ctx[(b * 2048 + srowg) * 1024 + h * 64 + nb * 16 + m] =
                    __float2bfloat16(oacc[nb][r] * inv);
        }
        __syncthreads();
    }
}

// ---------------------------------------------------------------------------
// Kernel 3: output projection, 128x128 tile — m97-class staging (round 4).
// grid = (32, 8), block = 256.
// ---------------------------------------------------------------------------
__global__ __launch_bounds__(256, 1) void gemm_out(
    const bf16* __restrict__ A,
    const void* __restrict__ wor, const bf16* __restrict__ Woc,
    const void* __restrict__ xr,
    void* __restrict__ out)
{
    const bool f32in = inputs_are_fp32((const unsigned short*)xr);
    const bf16* W = f32in ? Woc : (const bf16*)wor;

    __shared__ __align__(16) short smem[16384];   // 2 x (A+B) dbuf, 32768 B

    const int m0 = blockIdx.x * 128;
    const int n0 = blockIdx.y * 128;
    const int tid  = threadIdx.x;
    const int lane = tid & 63;
    const int wave = tid >> 6;
    const int wr = wave >> 1, wc = wave & 1;
    const int m = lane & 15, q = lane >> 4;

    const int stgrow = wave * 32 + (lane >> 2);
    const int ksegsh = (((lane & 3) ^ ((lane >> 3) & 3)) * 8);
    const bf16* Ag = A + (m0 + stgrow) * 1024 + ksegsh;
    const bf16* Bg = W + (n0 + stgrow) * 1024 + ksegsh;
    char* const smemB = (char*)smem;
    const int aoff = ((q ^ ((m >> 1) & 3)) * 8);

    f32x4 acc[4][4];
    #pragma unroll
    for (int mi = 0; mi < 4; ++mi)
        #pragma unroll
        for (int ni = 0; ni < 4; ++ni)
            acc[mi][ni] = (f32x4){0.f, 0.f, 0.f, 0.f};

    {
        char* la = smemB + wave * 2048;
        char* lb = smemB + 8192 + wave * 2048;
        gload16(Ag,            la);
        gload16(Ag + 16 * 1024, la + 1024);
        gload16(Bg,            lb);
        gload16(Bg + 16 * 1024, lb + 1024);
    }

    for (int k0 = 0; k0 < 1024; k0 += 32) {
        const int bs = (k0 >> 5) & 1;
        __syncthreads();
        if (k0 + 32 < 1024) {
            char* la = smemB + (bs ^ 1) * 16384 + wave * 2048;
            char* lb = la + 8192;
            gload16(Ag + (k0 + 32),             la);
            gload16(Ag + (k0 + 32) + 16 * 1024, la + 1024);
            gload16(Bg + (k0 + 32),             lb);
            gload16(Bg + (k0 + 32) + 16 * 1024, lb + 1024);
        }

        const short* As = smem + bs * 8192;
        const short* Bs = As + 4096;
        short8 af[4], bfr[4];
        #pragma unroll
        for (int mi = 0; mi < 4; ++mi)
            af[mi] = *(const short8*)&As[(wr * 64 + mi * 16 + m) * 32 + aoff];
        #pragma unroll
        for (int ni = 0; ni < 4; ++ni)
            bfr[ni] = *(const short8*)&Bs[(wc * 64 + ni * 16 + m) * 32 + aoff];
        #pragma unroll
        for (int mi = 0; mi < 4; ++mi)
            #pragma unroll
            for (int ni = 0; ni < 4; ++ni)
                acc[mi][ni] = MFMA16(af[mi], bfr[ni], acc[mi][ni]);
    }

    #pragma unroll
    for (int mi = 0; mi < 4; ++mi)
        #pragma unroll
        for (int ni = 0; ni < 4; ++ni)
            #pragma unroll
            for (int r = 0; r < 4; ++r) {
                int gm = m0 + wr * 64 + mi * 16 + q * 4 + r;
                int gn = n0 + wc * 64 + ni * 16 + m;
                int idx = gm * 1024 + gn;
                if (f32in) ((float*)out)[idx] = acc[mi][ni][r];
                else       ((bf16*)out)[idx]  = __float2bfloat16(acc[mi][ni][r]);
            }
}

// ---------------------------------------------------------------------------
extern "C" void kernel_launch(void* const* d_in, const int* in_sizes, int n_in,
                              void* d_out, int out_size, void* d_ws, size_t ws_size,
                              hipStream_t stream)
{
    const void* x_raw  = d_in[0];
    const void* Wq_raw = d_in[1];
    const void* Wk_raw = d_in[2];
    const void* Wv_raw = d_in[3];
    const void* Wo_raw = d_in[4];
    const int*  pos    = (const int*)d_in[5];

    char* ws = (char*)d_ws;
    bf16* Xc  = (bf16*)ws;                                    // 8 MB
    bf16* Wqc = (bf16*)(ws + 8388608);                        // 2 MB each
    bf16* Wkc = (bf16*)(ws + 8388608 + 2097152);
    bf16* Wvc = (bf16*)(ws + 8388608 + 2 * 2097152);
    bf16* Woc = (bf16*)(ws + 8388608 + 3 * 2097152);
    bf16* Qb  = (bf16*)(ws + 8388608 + 4 * 2097152);          // 8 MB each
    bf16* Kb  = Qb + 4194304;
    bf16* Vt  = Kb + 4194304;
    bf16* ctx = Vt + 4194304;
    float2* rtab = (float2*)(ctx + 4194304);                  // 512 KB

    convert_all<<<16640, 256, 0, stream>>>(
        x_raw, Wq_raw, Wk_raw, Wv_raw, Wo_raw,
        (unsigned int*)Xc, (unsigned int*)Wqc, (unsigned int*)Wkc,
        (unsigned int*)Wvc, (unsigned int*)Woc, pos, rtab);

    gemm_qkv_rope<<<dim3(32, 24), 256, 0, stream>>>(
        x_raw, Wq_raw, Wk_raw, Wv_raw, Xc, Wqc, Wkc, Wvc, rtab, Qb, Kb, Vt);
    flash_attn<<<dim3(16, 16, 2), 256, 0, stream>>>(Qb, Kb, Vt, ctx);
    gemm_out<<<dim3(32, 8), 256, 0, stream>>>(ctx, Wo_raw, Woc, x_raw, d_out);
}

// Round 13
// 185.460 us; speedup vs baseline: 1.0823x; 1.0344x over previous
//
#include <hip/hip_runtime.h>
#include <hip/hip_bf16.h>
#include <math.h>

typedef __hip_bfloat16 bf16;
typedef __attribute__((ext_vector_type(8))) short short8;
typedef __attribute__((ext_vector_type(4))) float f32x4;
typedef __attribute__((ext_vector_type(4))) unsigned int u32x4;

#define MFMA16(A, B, C) __builtin_amdgcn_mfma_f32_16x16x32_bf16((A), (B), (C), 0, 0, 0)
#define NEG_BIG (-1e30f)
#define EXP2(x) __builtin_amdgcn_exp2f(x)
// 0.125 (1/sqrt(d_k)) * log2(e): folded into Q at projection time -> scores in log2 domain
#define QSCALE 0.18033688011112042f
// defer-max threshold (log2 domain): skip O-rescale while P stays <= 2^8
#define RESCALE_THR 8.0f

// two-register half-swaps (gfx950)
#define P32SWAP(a, b) asm("v_permlane32_swap_b32 %0, %1" : "+v"(a), "+v"(b))
#define P16SWAP(a, b) asm("v_permlane16_swap_b32 %0, %1" : "+v"(a), "+v"(b))

static __device__ __forceinline__ unsigned int cvt_pk_bf16(float lo, float hi) {
    unsigned int r;
    asm("v_cvt_pk_bf16_f32 %0, %1, %2" : "=v"(r) : "v"(lo), "v"(hi));
    return r;
}

// async global->LDS, 16B per lane; LDS dest is wave-uniform base + lane*16
static __device__ __forceinline__ void gload16(const bf16* g, void* l) {
    __builtin_amdgcn_global_load_lds(
        (const __attribute__((address_space(1))) void*)g,
        (__attribute__((address_space(3))) void*)l,
        16, 0, 0);
}

// fp32 -> bf16 round-to-nearest-even via bit ops
static __device__ __forceinline__ unsigned short f32_to_bf16_rne(float f) {
    unsigned int u = __float_as_uint(f);
    unsigned int rnd = 0x7FFFu + ((u >> 16) & 1u);
    return (unsigned short)((u + rnd) >> 16);
}
static __device__ __forceinline__ unsigned int pack2_bf16(float lo, float hi) {
    return ((unsigned int)f32_to_bf16_rne(hi) << 16) | f32_to_bf16_rne(lo);
}

// In-kernel dtype detection (wave-uniform): scan first 64 shorts of x.
static __device__ __forceinline__ bool inputs_are_fp32(const unsigned short* x16) {
    int lane = threadIdx.x & 63;
    int e = (x16[lane] >> 7) & 0xFF;
    unsigned long long ball = __ballot(e >= 133);
    return __popcll(ball) >= 4;
}

// ---------------------------------------------------------------------------
// Kernel 0: fused RoPE-table + bf16 canonicalization, 16B/lane vectorized
// (round-12). Blocks >= 4096: rope cos/sin table (dtype-independent).
// Blocks < 4096: bf16 copies, each thread = 8 floats -> 1 uint4.
// ---------------------------------------------------------------------------
__global__ __launch_bounds__(256) void convert_all(
    const void* __restrict__ xs, const void* __restrict__ wq,
    const void* __restrict__ wk, const void* __restrict__ wv,
    const void* __restrict__ wo,
    u32x4* __restrict__ Xc, u32x4* __restrict__ Wqc,
    u32x4* __restrict__ Wkc, u32x4* __restrict__ Wvc,
    u32x4* __restrict__ Woc,
    const int* __restrict__ pos, float2* __restrict__ rtab)
{
    if (blockIdx.x >= 4096) {
        int i = (blockIdx.x - 4096) * 256 + threadIdx.x;   // 0..65535
        int s = i >> 5, p = i & 31;
        float freq = __expf((float)p * -0.28782313662425575f);
        float ang  = (float)pos[s] * freq;
        float sn, c;
        sincosf(ang, &sn, &c);
        rtab[i] = make_float2(c, sn);
        return;
    }
    if (!inputs_are_fp32((const unsigned short*)xs)) return;
    int i = blockIdx.x * 256 + threadIdx.x;  // 0 .. 1048575 (uint4 index)
    const float4* src;
    u32x4* dst;
    int off;
    if (i < 524288) { src = (const float4*)xs; dst = Xc; off = i; }
    else {
        int j = i - 524288;
        int t = j >> 17;          // 0..3
        off = j & 131071;
        src = (const float4*)((t == 0) ? wq : (t == 1) ? wk : (t == 2) ? wv : wo);
        dst = (t == 0) ? Wqc : (t == 1) ? Wkc : (t == 2) ? Wvc : Woc;
    }
    float4 a = src[2 * off], b = src[2 * off + 1];
    u32x4 o;
    o[0] = pack2_bf16(a.x, a.y);
    o[1] = pack2_bf16(a.z, a.w);
    o[2] = pack2_bf16(b.x, b.y);
    o[3] = pack2_bf16(b.z, b.w);
    dst[off] = o;
}

// ---------------------------------------------------------------------------
// Kernel 1: QKV projection GEMM, 128x128 tile, BK=32 (round-4 m97-class:
// dbuf linear LDS + global_load_lds w16 + source-side swizzle, 1 barrier/K).
// grid = (32 m-tiles, 24 = 3 weights x 8 n-tiles), block = 256 (2x2 waves).
// Q,K: RoPE-table epilogue [b,h,s,d]. V: LDS-transposed [b,h,d,s].
// Q pre-scaled by 0.125*log2(e) -> flash softmax in exp2 domain.
// ---------------------------------------------------------------------------
__global__ __launch_bounds__(256, 1) void gemm_qkv_rope(
    const void* __restrict__ xr,
    const void* __restrict__ wqr, const void* __restrict__ wkr,
    const void* __restrict__ wvr,
    const bf16* __restrict__ Xc,
    const bf16* __restrict__ Wqc, const bf16* __restrict__ Wkc,
    const bf16* __restrict__ Wvc,
    const float2* __restrict__ rtab,
    bf16* __restrict__ Qb, bf16* __restrict__ Kb, bf16* __restrict__ Vt)
{
    const bool f32in = inputs_are_fp32((const unsigned short*)xr);
    const bf16* X = f32in ? Xc : (const bf16*)xr;

    // union: dbuf staging (2 x (A[128][32]+B[128][32]) = 16384 shorts)
    //        vs V-transpose tile (128x132 = 16896 shorts)
    __shared__ __align__(16) short smem[128 * 132];   // 33792 B

    const int m0   = blockIdx.x * 128;
    const int wsel = blockIdx.y >> 3;            // 0=Q, 1=K, 2=V
    const int n0   = (blockIdx.y & 7) * 128;
    const bf16* W  = (wsel == 0) ? (f32in ? Wqc : (const bf16*)wqr)
                   : (wsel == 1) ? (f32in ? Wkc : (const bf16*)wkr)
                                 : (f32in ? Wvc : (const bf16*)wvr);

    const int tid  = threadIdx.x;
    const int lane = tid & 63;
    const int wave = tid >> 6;
    const int wr   = wave >> 1, wc = wave & 1;   // 2x2 waves, each 64x64
    const int m    = lane & 15;
    const int q    = lane >> 4;

    const int stgrow = wave * 32 + (lane >> 2);
    const int ksegsh = (((lane & 3) ^ ((lane >> 3) & 3)) * 8);   // shorts
    const bf16* Ag = X + (m0 + stgrow) * 1024 + ksegsh;
    const bf16* Bg = W + (n0 + stgrow) * 1024 + ksegsh;
    char* const smemB = (char*)smem;
    const int aoff = ((q ^ ((m >> 1) & 3)) * 8);   // shorts within 32-short row

    f32x4 acc[4][4];
    #pragma unroll
    for (int mi = 0; mi < 4; ++mi)
        #pragma unroll
        for (int ni = 0; ni < 4; ++ni)
            acc[mi][ni] = (f32x4){0.f, 0.f, 0.f, 0.f};

    {
        char* la = smemB + wave * 2048;           // A buf0 + wave rows
        char* lb = smemB + 8192 + wave * 2048;    // B buf0
        gload16(Ag,            la);
        gload16(Ag + 16 * 1024, la + 1024);       // +16 rows
        gload16(Bg,            lb);
        gload16(Bg + 16 * 1024, lb + 1024);
    }

    for (int k0 = 0; k0 < 1024; k0 += 32) {
        const int bs = (k0 >> 5) & 1;
        __syncthreads();                           // buf[bs] landed (vmcnt drain)
        if (k0 + 32 < 1024) {                      // stage next into buf[bs^1]
            char* la = smemB + (bs ^ 1) * 16384 + wave * 2048;
            char* lb = la + 8192;
            gload16(Ag + (k0 + 32),             la);
            gload16(Ag + (k0 + 32) + 16 * 1024, la + 1024);
            gload16(Bg + (k0 + 32),             lb);
            gload16(Bg + (k0 + 32) + 16 * 1024, lb + 1024);
        }

        const short* As = smem + bs * 8192;        // shorts
        const short* Bs = As + 4096;
        short8 af[4], bfr[4];
        #pragma unroll
        for (int mi = 0; mi < 4; ++mi)
            af[mi] = *(const short8*)&As[(wr * 64 + mi * 16 + m) * 32 + aoff];
        #pragma unroll
        for (int ni = 0; ni < 4; ++ni)
            bfr[ni] = *(const short8*)&Bs[(wc * 64 + ni * 16 + m) * 32 + aoff];
        #pragma unroll
        for (int mi = 0; mi < 4; ++mi)
            #pragma unroll
            for (int ni = 0; ni < 4; ++ni)
                acc[mi][ni] = MFMA16(af[mi], bfr[ni], acc[mi][ni]);
    }

    const int bb  = m0 >> 11;
    const int s0  = m0 & 2047;
    const int hh0 = n0 >> 6;          // first of 2 heads in this n-tile

    if (wsel < 2) {
        bf16* dstb = (wsel == 0) ? Qb : Kb;
        const float sc = (wsel == 0) ? QSCALE : 1.0f;
        #pragma unroll
        for (int mi = 0; mi < 4; ++mi)
            #pragma unroll
            for (int ni = 0; ni < 4; ++ni)
                #pragma unroll
                for (int r = 0; r < 4; ++r) {
                    int s  = s0 + wr * 64 + mi * 16 + q * 4 + r;
                    int gn = n0 + wc * 64 + ni * 16 + m;
                    int hh = gn >> 6, d = gn & 63;
                    float v = acc[mi][ni][r];
                    float partner = __shfl_xor(v, 1);
                    float2 cs = rtab[s * 32 + (d >> 1)];
                    float outv = ((d & 1) == 0) ? (cs.x * v - cs.y * partner)
                                                : (cs.y * partner + cs.x * v);
                    dstb[((bb * 16 + hh) * 2048 + s) * 64 + d] =
                        __float2bfloat16(outv * sc);
                }
    } else {
        __syncthreads();   // all staging reads done before alias overwrite
        #pragma unroll
        for (int mi = 0; mi < 4; ++mi)
            #pragma unroll
            for (int ni = 0; ni < 4; ++ni)
                #pragma unroll
                for (int r = 0; r < 4; ++r) {
                    int ls = wr * 64 + mi * 16 + q * 4 + r;   // local s 0..127
                    int ld = wc * 64 + ni * 16 + m;           // local d 0..127
                    bf16 hv = __float2bfloat16(acc[mi][ni][r]);
                    smem[ld * 132 + ls] = *(short*)&hv;
                }
        __syncthreads();
        int dd = tid >> 1;            // 0..127: head hh0 + (dd>>6), d = dd&63
        int half = tid & 1;
        bf16* vrow = Vt + ((bb * 16 + hh0 + (dd >> 6)) * 64 + (dd & 63)) * 2048
                        + s0 + half * 64;
        #pragma unroll
        for (int j = 0; j < 8; ++j)
            *(short8*)(vrow + j * 8) =
                *(const short8*)&smem[dd * 132 + half * 64 + j * 8];
    }
}

// ---------------------------------------------------------------------------
// Kernel 2: causal flash attention — round-4 proven body + T13 defer-max
// (round-12). When __all(rm - mi_s <= 8) the max-update/alpha/li-scale/
// O-rescale block is skipped (wave-uniform branch); P bounded by 2^8,
// carried by bf16's relative precision and cancelled by 1/li at the end.
// First iteration always rescales (mi_s = -1e30).
// ---------------------------------------------------------------------------
#define KST 72
#define VST 136

__global__ __launch_bounds__(256) void flash_attn(
    const bf16* __restrict__ Qb, const bf16* __restrict__ Kb,
    const bf16* __restrict__ Vt, bf16* __restrict__ ctx)
{
    const int pair = blockIdx.x;      // 0..15
    const int h = blockIdx.y, b = blockIdx.z;
    const int bh = b * 16 + h;

    __shared__ __align__(16) short Ks[128 * KST];
    __shared__ __align__(16) short Vs[64 * VST];

    const int tid  = threadIdx.x;
    const int lane = tid & 63;
    const int wave = tid >> 6;
    const int m = lane & 15;
    const int q = lane >> 4;

    const int krow = tid >> 1;
    const int kseg = (tid & 1) * 32;
    const int ksw  = ((krow >> 3) & 3) << 3;   // staging swizzle (shorts)
    const int vrow = tid >> 2;
    const int vseg = (tid & 3) * 32;

    const bf16* Kg = Kb + bh * 2048 * 64 + krow * 64   + kseg;
    const bf16* Vg = Vt + bh * 64 * 2048 + vrow * 2048 + vseg;

    for (int part = 0; part < 2; ++part) {
        const int qtile = (part == 0) ? pair : 31 - pair;
        const int nk2 = (qtile + 2) >> 1;
        const int rowbase = qtile * 64 + wave * 16;

        const bf16* Qp = Qb + (bh * 2048 + rowbase + m) * 64;
        short8 qf0 = *(const short8*)(Qp + q * 8);
        short8 qf1 = *(const short8*)(Qp + 32 + q * 8);

        f32x4 oacc[4];
        #pragma unroll
        for (int nb = 0; nb < 4; ++nb) oacc[nb] = (f32x4){0.f, 0.f, 0.f, 0.f};
        float mi_s = NEG_BIG, li_s = 0.f;   // per-lane softmax row = rowbase + m

        short8 kr[4], vr[4];
        #pragma unroll
        for (int j = 0; j < 4; ++j) {
            kr[j] = *(const short8*)(Kg + j * 8);
            vr[j] = *(const short8*)(Vg + j * 8);
        }

        for (int kt2 = 0; kt2 < nk2; ++kt2) {
            __syncthreads();
            #pragma unroll
            for (int j = 0; j < 4; ++j) {
                *(short8*)&Ks[krow * KST + ((kseg + j * 8) ^ ksw)] = kr[j];
                *(short8*)&Vs[vrow * VST + vseg + j * 8] = vr[j];
            }
            __syncthreads();

            if (kt2 + 1 < nk2) {
                #pragma unroll
                for (int j = 0; j < 4; ++j) {
                    kr[j] = *(const short8*)(Kg + (kt2 + 1) * 8192 + j * 8);
                    vr[j] = *(const short8*)(Vg + (kt2 + 1) * 128  + j * 8);
                }
            }

            // swapped QK^T: S[q-row = m][key = kt2*128 + nc*16 + q*4 + r]
            f32x4 sacc[8];
            #pragma unroll
            for (int nc = 0; nc < 8; ++nc) {
                int row = nc * 16 + m;
                int sw  = ((row >> 3) & 3) << 3;
                const short* kp = &Ks[row * KST];
                short8 kf0 = *(const short8*)&kp[(q * 8) ^ sw];
                short8 kf1 = *(const short8*)&kp[32 + ((q * 8) ^ sw)];
                f32x4 z = {0.f, 0.f, 0.f, 0.f};
                z = MFMA16(kf0, qf0, z);
                z = MFMA16(kf1, qf1, z);
                sacc[nc] = z;
            }

            // causal mask (log2-domain scores; scale folded into Q)
            if (kt2 * 128 + 127 > rowbase) {
                int rowg = rowbase + m;
                #pragma unroll
                for (int nc = 0; nc < 8; ++nc)
                    #pragma unroll
                    for (int r = 0; r < 4; ++r) {
                        int col = kt2 * 128 + nc * 16 + q * 4 + r;
                        if (col > rowg) sacc[nc][r] = NEG_BIG;
                    }
            }

            // in-lane tree max + cross-q butterfly (lanes m,q=0..3 share row m)
            float tm[8];
            #pragma unroll
            for (int nc = 0; nc < 8; ++nc)
                tm[nc] = fmaxf(fmaxf(sacc[nc][0], sacc[nc][1]),
                               fmaxf(sacc[nc][2], sacc[nc][3]));
            float rm = fmaxf(fmaxf(fmaxf(tm[0], tm[1]), fmaxf(tm[2], tm[3])),
                             fmaxf(fmaxf(tm[4], tm[5]), fmaxf(tm[6], tm[7])));
            rm = fmaxf(rm, __shfl_xor(rm, 16));
            rm = fmaxf(rm, __shfl_xor(rm, 32));

            // T13 defer-max: only rescale when some row grew past THR
            if (!__all(rm - mi_s <= RESCALE_THR)) {
                float mnew  = fmaxf(mi_s, rm);
                float alpha = EXP2(mi_s - mnew);   // exp2(-inf)=0 on first tile
                mi_s = mnew;
                li_s *= alpha;
                float ar[4];
                #pragma unroll
                for (int r = 0; r < 4; ++r) ar[r] = __shfl(alpha, q * 20 + r);
                #pragma unroll
                for (int nb = 0; nb < 4; ++nb)
                    #pragma unroll
                    for (int r = 0; r < 4; ++r) oacc[nb][r] *= ar[r];
            }

            #pragma unroll
            for (int nc = 0; nc < 8; ++nc)
                #pragma unroll
                for (int r = 0; r < 4; ++r)
                    sacc[nc][r] = EXP2(sacc[nc][r] - mi_s);  // masked -> 0

            float ts[8];
            #pragma unroll
            for (int nc = 0; nc < 8; ++nc)
                ts[nc] = (sacc[nc][0] + sacc[nc][1]) + (sacc[nc][2] + sacc[nc][3]);
            float asum = ((ts[0] + ts[1]) + (ts[2] + ts[3]))
                       + ((ts[4] + ts[5]) + (ts[6] + ts[7]));
            asum += __shfl_xor(asum, 16);
            asum += __shfl_xor(asum, 32);
            li_s += asum;

            // pack P pairs to bf16 and route into PV A-fragments in-register.
            unsigned int u0[8], u1[8];
            #pragma unroll
            for (int nc = 0; nc < 8; ++nc) {
                u0[nc] = cvt_pk_bf16(sacc[nc][0], sacc[nc][1]);
                u1[nc] = cvt_pk_bf16(sacc[nc][2], sacc[nc][3]);
            }
            short8 pa[4];
            #pragma unroll
            for (int ck = 0; ck < 4; ++ck) {
                unsigned int x0 = u0[2 * ck], y0 = u0[2 * ck + 1];
                P32SWAP(x0, y0);
                P16SWAP(x0, y0);
                unsigned int x1 = u1[2 * ck], y1 = u1[2 * ck + 1];
                P32SWAP(x1, y1);
                P16SWAP(x1, y1);
                union { u32x4 u; short8 s; } uu;
                uu.u = (u32x4){x0, x1, y0, y1};
                pa[ck] = uu.s;
            }

            #pragma unroll
            for (int nb = 0; nb < 4; ++nb)
                #pragma unroll
                for (int ck = 0; ck < 4; ++ck) {
                    short8 vf = *(const short8*)&Vs[(nb * 16 + m) * VST + ck * 32 + q * 8];
                    oacc[nb] = MFMA16(pa[ck], vf, oacc[nb]);
                }
        }

        // epilogue: li for output row q*4+r lives in lanes m = q*4+r
        float lr[4];
        #pragma unroll
        for (int r = 0; r < 4; ++r) lr[r] = __shfl(li_s, q * 20 + r);
        #pragma unroll
        for (int r = 0; r < 4; ++r) {
            float inv = 1.f / lr[r];
            int srowg = qtile * 64 + wave * 16 + q * 4 + r;
            #pragma unroll
            for (int nb = 0; nb < 4; ++nb)
                ctx[(b * 2048 + srowg) * 1024 + h * 64 + nb * 16 + m] =
                    __float2bfloat16(oacc[nb][r] * inv);
        }
        __syncthreads();
    }
}

// ---------------------------------------------------------------------------
// Kernel 3: output projection, 128x128 tile — m97-class staging (round 4).
// grid = (32, 8), block = 256.
// ---------------------------------------------------------------------------
__global__ __launch_bounds__(256, 1) void gemm_out(
    const bf16* __restrict__ A,
    const void* __restrict__ wor, const bf16* __restrict__ Woc,
    const void* __restrict__ xr,
    void* __restrict__ out)
{
    const bool f32in = inputs_are_fp32((const unsigned short*)xr);
    const bf16* W = f32in ? Woc : (const bf16*)wor;

    __shared__ __align__(16) short smem[16384];   // 2 x (A+B) dbuf, 32768 B

    const int m0 = blockIdx.x * 128;
    const int n0 = blockIdx.y * 128;
    const int tid  = threadIdx.x;
    const int lane = tid & 63;
    const int wave = tid >> 6;
    const int wr = wave >> 1, wc = wave & 1;
    const int m = lane & 15, q = lane >> 4;

    const int stgrow = wave * 32 + (lane >> 2);
    const int ksegsh = (((lane & 3) ^ ((lane >> 3) & 3)) * 8);
    const bf16* Ag = A + (m0 + stgrow) * 1024 + ksegsh;
    const bf16* Bg = W + (n0 + stgrow) * 1024 + ksegsh;
    char* const smemB = (char*)smem;
    const int aoff = ((q ^ ((m >> 1) & 3)) * 8);

    f32x4 acc[4][4];
    #pragma unroll
    for (int mi = 0; mi < 4; ++mi)
        #pragma unroll
        for (int ni = 0; ni < 4; ++ni)
            acc[mi][ni] = (f32x4){0.f, 0.f, 0.f, 0.f};

    {
        char* la = smemB + wave * 2048;
        char* lb = smemB + 8192 + wave * 2048;
        gload16(Ag,            la);
        gload16(Ag + 16 * 1024, la + 1024);
        gload16(Bg,            lb);
        gload16(Bg + 16 * 1024, lb + 1024);
    }

    for (int k0 = 0; k0 < 1024; k0 += 32) {
        const int bs = (k0 >> 5) & 1;
        __syncthreads();
        if (k0 + 32 < 1024) {
            char* la = smemB + (bs ^ 1) * 16384 + wave * 2048;
            char* lb = la + 8192;
            gload16(Ag + (k0 + 32),             la);
            gload16(Ag + (k0 + 32) + 16 * 1024, la + 1024);
            gload16(Bg + (k0 + 32),             lb);
            gload16(Bg + (k0 + 32) + 16 * 1024, lb + 1024);
        }

        const short* As = smem + bs * 8192;
        const short* Bs = As + 4096;
        short8 af[4], bfr[4];
        #pragma unroll
        for (int mi = 0; mi < 4; ++mi)
            af[mi] = *(const short8*)&As[(wr * 64 + mi * 16 + m) * 32 + aoff];
        #pragma unroll
        for (int ni = 0; ni < 4; ++ni)
            bfr[ni] = *(const short8*)&Bs[(wc * 64 + ni * 16 + m) * 32 + aoff];
        #pragma unroll
        for (int mi = 0; mi < 4; ++mi)
            #pragma unroll
            for (int ni = 0; ni < 4; ++ni)
                acc[mi][ni] = MFMA16(af[mi], bfr[ni], acc[mi][ni]);
    }

    #pragma unroll
    for (int mi = 0; mi < 4; ++mi)
        #pragma unroll
        for (int ni = 0; ni < 4; ++ni)
            #pragma unroll
            for (int r = 0; r < 4; ++r) {
                int gm = m0 + wr * 64 + mi * 16 + q * 4 + r;
                int gn = n0 + wc * 64 + ni * 16 + m;
                int idx = gm * 1024 + gn;
                if (f32in) ((float*)out)[idx] = acc[mi][ni][r];
                else       ((bf16*)out)[idx]  = __float2bfloat16(acc[mi][ni][r]);
            }
}

// ---------------------------------------------------------------------------
extern "C" void kernel_launch(void* const* d_in, const int* in_sizes, int n_in,
                              void* d_out, int out_size, void* d_ws, size_t ws_size,
                              hipStream_t stream)
{
    const void* x_raw  = d_in[0];
    const void* Wq_raw = d_in[1];
    const void* Wk_raw = d_in[2];
    const void* Wv_raw = d_in[3];
    const void* Wo_raw = d_in[4];
    const int*  pos    = (const int*)d_in[5];

    char* ws = (char*)d_ws;
    bf16* Xc  = (bf16*)ws;                                    // 8 MB
    bf16* Wqc = (bf16*)(ws + 8388608);                        // 2 MB each
    bf16* Wkc = (bf16*)(ws + 8388608 + 2097152);
    bf16* Wvc = (bf16*)(ws + 8388608 + 2 * 2097152);
    bf16* Woc = (bf16*)(ws + 8388608 + 3 * 2097152);
    bf16* Qb  = (bf16*)(ws + 8388608 + 4 * 2097152);          // 8 MB each
    bf16* Kb  = Qb + 4194304;
    bf16* Vt  = Kb + 4194304;
    bf16* ctx = Vt + 4194304;
    float2* rtab = (float2*)(ctx + 4194304);                  // 512 KB

    convert_all<<<4352, 256, 0, stream>>>(
        x_raw, Wq_raw, Wk_raw, Wv_raw, Wo_raw,
        (u32x4*)Xc, (u32x4*)Wqc, (u32x4*)Wkc,
        (u32x4*)Wvc, (u32x4*)Woc, pos, rtab);

    gemm_qkv_rope<<<dim3(32, 24), 256, 0, stream>>>(
        x_raw, Wq_raw, Wk_raw, Wv_raw, Xc, Wqc, Wkc, Wvc, rtab, Qb, Kb, Vt);
    flash_attn<<<dim3(16, 16, 2), 256, 0, stream>>>(Qb, Kb, Vt, ctx);
    gemm_out<<<dim3(32, 8), 256, 0, stream>>>(ctx, Wo_raw, Woc, x_raw, d_out);
}